// Round 9
// baseline (972.778 us; speedup 1.0000x reference)
//
#include <hip/hip_runtime.h>

#define N_NODES 50000
#define E_EDGES 1600000
#define E2 (E_EDGES + N_NODES)   // 1,650,000 with self loops
#define HEADS 4
#define F 256
#define OUTC 10
#define BN_EPS 1e-5f
#define NEG_SLOPE 0.2f
#define SB 1024                  // scan block size
#define NB ((N_NODES + SB - 1) / SB)   // 49 scan blocks

static_assert(N_NODES % 4 == 0, "grid_nw exact");

typedef __attribute__((ext_vector_type(8))) short short8;
typedef __attribute__((ext_vector_type(4))) float f32x4;

__device__ __forceinline__ unsigned short f2bf(float f) {
    unsigned int u = __float_as_uint(f);
    unsigned int r = (u + 0x7fffu + ((u >> 16) & 1u)) >> 16;
    return (unsigned short)r;
}
__device__ __forceinline__ float bf2f(unsigned short b) {
    return __uint_as_float(((unsigned int)b) << 16);
}

// ---------------- convert X f32 -> bf16 ----------------
__global__ __launch_bounds__(256) void convert_x(
    const float* __restrict__ X, unsigned short* __restrict__ Xb)
{
    int i = blockIdx.x * blockDim.x + threadIdx.x;
    const int total = N_NODES * 128 / 4;
    if (i >= total) return;
    float4 v = reinterpret_cast<const float4*>(X)[i];
    ushort4 o = { f2bf(v.x), f2bf(v.y), f2bf(v.z), f2bf(v.w) };
    reinterpret_cast<ushort4*>(Xb)[i] = o;
}

// ---------------- convert W1 [128,256] f32 -> WT1b [256,128] bf16 ------
__global__ __launch_bounds__(256) void convert_w1T(
    const float* __restrict__ W1, unsigned short* __restrict__ WT)
{
    const int k = blockIdx.x;        // 128 blocks
    const int n = threadIdx.x;       // 256 threads, coalesced read
    WT[n * 128 + k] = f2bf(W1[k * 256 + n]);
}

// ---------------- CSR build (integer atomics only) ----------------
__global__ __launch_bounds__(256) void count_deg(
    const int* __restrict__ eidx, int* __restrict__ deg)
{
    int e = blockIdx.x * blockDim.x + threadIdx.x;
    if (e >= E2) return;
    int dst = (e < E_EDGES) ? eidx[E_EDGES + e] : e - E_EDGES;
    atomicAdd(&deg[dst], 1);
}

__global__ __launch_bounds__(SB) void scan_blocks(
    const int* __restrict__ deg, int* __restrict__ rowptr, int* __restrict__ bsum)
{
    __shared__ int sm[SB];
    const int t = threadIdx.x;
    const int idx = blockIdx.x * SB + t;
    int v = (idx < N_NODES) ? deg[idx] : 0;
    sm[t] = v;
    __syncthreads();
    for (int off = 1; off < SB; off <<= 1) {
        int u = (t >= off) ? sm[t - off] : 0;
        __syncthreads();
        sm[t] += u;
        __syncthreads();
    }
    if (idx < N_NODES) rowptr[idx] = sm[t] - v;
    if (t == SB - 1) bsum[blockIdx.x] = sm[t];
}

__global__ __launch_bounds__(64) void scan_bsums(
    const int* __restrict__ bsum, int* __restrict__ boff, int* __restrict__ rowptr)
{
    if (threadIdx.x == 0) {
        int run = 0;
        for (int b = 0; b < NB; b++) { boff[b] = run; run += bsum[b]; }
        rowptr[N_NODES] = run;
    }
}

__global__ __launch_bounds__(SB) void scan_add(
    int* __restrict__ rowptr, const int* __restrict__ boff)
{
    const int idx = blockIdx.x * SB + threadIdx.x;
    if (idx < N_NODES) rowptr[idx] += boff[blockIdx.x];
}

__global__ __launch_bounds__(256) void scatter_edges(
    const int* __restrict__ eidx, const int* __restrict__ rowptr,
    int* __restrict__ cursor, int* __restrict__ esrc)
{
    int e = blockIdx.x * blockDim.x + threadIdx.x;
    if (e >= E2) return;
    int src, dst;
    if (e < E_EDGES) { src = eidx[e]; dst = eidx[E_EDGES + e]; }
    else             { src = dst = e - E_EDGES; }
    int pos = atomicAdd(&cursor[dst], 1);
    esrc[rowptr[dst] + pos] = src;
}

// ------- MFMA GEMM + fused S/D: C = A@BT^T (+brow); S/D from f32 acc ---
template<int K, bool BROW>
__global__ __launch_bounds__(256) void gemm_sd(
    const unsigned short* __restrict__ A, const unsigned short* __restrict__ BT,
    const float* __restrict__ brow, const float* __restrict__ a_src,
    const float* __restrict__ a_dst, unsigned short* __restrict__ C,
    float* __restrict__ S, float* __restrict__ D)
{
    const int t = threadIdx.x;
    const int wave = t >> 6, lane = t & 63;
    const int lo = lane & 15, hi = lane >> 4;
    const int row0 = blockIdx.x * 64;
    const int nbase = wave * 64;

    int arow[4];
#pragma unroll
    for (int m = 0; m < 4; m++)
        arow[m] = min(row0 + m * 16 + lo, N_NODES - 1);   // never read unwritten ws

    f32x4 acc[4][4];
#pragma unroll
    for (int m = 0; m < 4; m++)
#pragma unroll
        for (int n = 0; n < 4; n++)
            acc[m][n] = (f32x4){0.f, 0.f, 0.f, 0.f};

    for (int k0 = 0; k0 < K; k0 += 32) {
        const int kk = k0 + hi * 8;
        short8 af[4], bfr[4];
#pragma unroll
        for (int m = 0; m < 4; m++)
            af[m] = *reinterpret_cast<const short8*>(A + (size_t)arow[m] * K + kk);
#pragma unroll
        for (int n = 0; n < 4; n++)
            bfr[n] = *reinterpret_cast<const short8*>(BT + (size_t)(nbase + n * 16 + lo) * K + kk);
#pragma unroll
        for (int m = 0; m < 4; m++)
#pragma unroll
            for (int n = 0; n < 4; n++)
                acc[m][n] = __builtin_amdgcn_mfma_f32_16x16x32_bf16(
                    af[m], bfr[n], acc[m][n], 0, 0, 0);
    }

    float bb[4], asv[4], adv[4];
#pragma unroll
    for (int n = 0; n < 4; n++) {
        int col = nbase + n * 16 + lo;
        bb[n]  = BROW ? brow[col] : 0.f;
        asv[n] = a_src[col];
        adv[n] = a_dst[col];
    }

#pragma unroll
    for (int m = 0; m < 4; m++) {
#pragma unroll
        for (int i = 0; i < 4; i++) {
            const int row = row0 + m * 16 + hi * 4 + i;
            const bool ok = row < N_NODES;
            float ps = 0.f, pd = 0.f;
#pragma unroll
            for (int n = 0; n < 4; n++) {
                float v = acc[m][n][i] + bb[n];
                ps += v * asv[n];
                pd += v * adv[n];
                if (ok) C[(size_t)row * F + nbase + n * 16 + lo] = f2bf(v);
            }
#pragma unroll
            for (int off = 1; off < 16; off <<= 1) {
                ps += __shfl_xor(ps, off, 64);
                pd += __shfl_xor(pd, off, 64);
            }
            if (lo == 0 && ok) {
                S[row * HEADS + wave] = ps;
                D[row * HEADS + wave] = pd;
            }
        }
    }
}

// ------- fused softmax + aggregation + bias + ReLU + batch stats -------
// EXACT R6 inner loop (measured 113.8 us, 0 bank conflicts): per-wave LDS
// staging of (src, w4), direct LDS-indexed reads, 8-deep ushort4 gather
// unroll. Fused stats epilogue (R7) kept.
__global__ __launch_bounds__(256) void gat_aggregate(
    const int* __restrict__ rowptr, const int* __restrict__ esrc,
    const float* __restrict__ S, const float* __restrict__ D,
    const unsigned short* __restrict__ XWb, const float* __restrict__ bias,
    unsigned short* __restrict__ Hb, float* __restrict__ st)
{
    __shared__ int   sbuf[4][64];
    __shared__ float wbuf[4][64][4];
    __shared__ float red_s[4][F];
    __shared__ float red_q[4][F];
    const int wv   = threadIdx.x >> 6;
    const int lane = threadIdx.x & 63;
    const int dst  = blockIdx.x * 4 + wv;        // always < N_NODES (N%4==0)
    const int beg = rowptr[dst], end = rowptr[dst + 1];
    const int h = lane >> 4;
    const float4 d4 = *reinterpret_cast<const float4*>(D + dst * HEADS);

    float ax = 0.f, ay = 0.f, az = 0.f, aw = 0.f, den = 0.f;

    for (int i = beg; i < end; i += 64) {
        const int nb = min(64, end - i);
        const bool valid = (i + lane < end);
        const int mysrc = valid ? esrc[i + lane] : 0;   // row 0 always valid
        float4 w4 = {0.f, 0.f, 0.f, 0.f};
        if (valid) {
            const float4 s4 = *reinterpret_cast<const float4*>(S + mysrc * HEADS);
            float z;
            z = s4.x + d4.x; w4.x = __expf(z > 0.f ? z : NEG_SLOPE * z);
            z = s4.y + d4.y; w4.y = __expf(z > 0.f ? z : NEG_SLOPE * z);
            z = s4.z + d4.z; w4.z = __expf(z > 0.f ? z : NEG_SLOPE * z);
            z = s4.w + d4.w; w4.w = __expf(z > 0.f ? z : NEG_SLOPE * z);
        }
        sbuf[wv][lane] = mysrc;
        *reinterpret_cast<float4*>(&wbuf[wv][lane][0]) = w4;

        int j = 0;
        for (; j + 7 < nb; j += 8) {
            int s0 = sbuf[wv][j + 0], s1 = sbuf[wv][j + 1];
            int s2 = sbuf[wv][j + 2], s3 = sbuf[wv][j + 3];
            int s4i = sbuf[wv][j + 4], s5 = sbuf[wv][j + 5];
            int s6 = sbuf[wv][j + 6], s7 = sbuf[wv][j + 7];
            float w0 = wbuf[wv][j + 0][h], w1 = wbuf[wv][j + 1][h];
            float w2 = wbuf[wv][j + 2][h], w3 = wbuf[wv][j + 3][h];
            float w4f = wbuf[wv][j + 4][h], w5 = wbuf[wv][j + 5][h];
            float w6 = wbuf[wv][j + 6][h], w7 = wbuf[wv][j + 7][h];
            ushort4 x0 = *reinterpret_cast<const ushort4*>(XWb + (size_t)s0 * F + lane * 4);
            ushort4 x1 = *reinterpret_cast<const ushort4*>(XWb + (size_t)s1 * F + lane * 4);
            ushort4 x2 = *reinterpret_cast<const ushort4*>(XWb + (size_t)s2 * F + lane * 4);
            ushort4 x3 = *reinterpret_cast<const ushort4*>(XWb + (size_t)s3 * F + lane * 4);
            ushort4 x4 = *reinterpret_cast<const ushort4*>(XWb + (size_t)s4i * F + lane * 4);
            ushort4 x5 = *reinterpret_cast<const ushort4*>(XWb + (size_t)s5 * F + lane * 4);
            ushort4 x6 = *reinterpret_cast<const ushort4*>(XWb + (size_t)s6 * F + lane * 4);
            ushort4 x7 = *reinterpret_cast<const ushort4*>(XWb + (size_t)s7 * F + lane * 4);
            ax += w0 * bf2f(x0.x) + w1 * bf2f(x1.x) + w2 * bf2f(x2.x) + w3 * bf2f(x3.x)
                + w4f * bf2f(x4.x) + w5 * bf2f(x5.x) + w6 * bf2f(x6.x) + w7 * bf2f(x7.x);
            ay += w0 * bf2f(x0.y) + w1 * bf2f(x1.y) + w2 * bf2f(x2.y) + w3 * bf2f(x3.y)
                + w4f * bf2f(x4.y) + w5 * bf2f(x5.y) + w6 * bf2f(x6.y) + w7 * bf2f(x7.y);
            az += w0 * bf2f(x0.z) + w1 * bf2f(x1.z) + w2 * bf2f(x2.z) + w3 * bf2f(x3.z)
                + w4f * bf2f(x4.z) + w5 * bf2f(x5.z) + w6 * bf2f(x6.z) + w7 * bf2f(x7.z);
            aw += w0 * bf2f(x0.w) + w1 * bf2f(x1.w) + w2 * bf2f(x2.w) + w3 * bf2f(x3.w)
                + w4f * bf2f(x4.w) + w5 * bf2f(x5.w) + w6 * bf2f(x6.w) + w7 * bf2f(x7.w);
            den += ((w0 + w1) + (w2 + w3)) + ((w4f + w5) + (w6 + w7));
        }
        for (; j < nb; j++) {
            int   src = sbuf[wv][j];
            float w = wbuf[wv][j][h];
            ushort4 xv = *reinterpret_cast<const ushort4*>(XWb + (size_t)src * F + lane * 4);
            ax += w * bf2f(xv.x); ay += w * bf2f(xv.y);
            az += w * bf2f(xv.z); aw += w * bf2f(xv.w);
            den += w;
        }
    }

    const float inv = 1.f / (den + 1e-16f);
    float4 bv = *reinterpret_cast<const float4*>(bias + lane * 4);
    float v0 = ax * inv + bv.x, v1 = ay * inv + bv.y;
    float v2 = az * inv + bv.z, v3 = aw * inv + bv.w;
    v0 = v0 > 0.f ? v0 : 0.f; v1 = v1 > 0.f ? v1 : 0.f;
    v2 = v2 > 0.f ? v2 : 0.f; v3 = v3 > 0.f ? v3 : 0.f;
    ushort4 o = { f2bf(v0), f2bf(v1), f2bf(v2), f2bf(v3) };
    *reinterpret_cast<ushort4*>(Hb + (size_t)dst * F + lane * 4) = o;

    f32x4 rs = {v0, v1, v2, v3};
    f32x4 rq = {v0 * v0, v1 * v1, v2 * v2, v3 * v3};
    *reinterpret_cast<f32x4*>(&red_s[wv][lane * 4]) = rs;
    *reinterpret_cast<f32x4*>(&red_q[wv][lane * 4]) = rq;
    __syncthreads();
    // block-level stats -> global atomics (f32; ULP-order jitter only)
    const int ch = threadIdx.x;
    float s = (red_s[0][ch] + red_s[1][ch]) + (red_s[2][ch] + red_s[3][ch]);
    float q = (red_q[0][ch] + red_q[1][ch]) + (red_q[2][ch] + red_q[3][ch]);
    atomicAdd(&st[ch], s);
    atomicAdd(&st[F + ch], q);
}

// ---------------- BN prep + brow (layer 1 -> layer 2 fold), 1 block ----
__global__ __launch_bounds__(256) void prep_brow(
    const float* __restrict__ st, const float* __restrict__ g,
    const float* __restrict__ be, const float* __restrict__ W2,
    float* __restrict__ scb, float* __restrict__ shb, float* __restrict__ brow)
{
    __shared__ float sh_l[F];
    const int t = threadIdx.x;
    const float inv_n = 1.f / (float)N_NODES;
    float mu = st[t] * inv_n;
    float var = st[F + t] * inv_n - mu * mu;
    float sc = rsqrtf(var + BN_EPS) * g[t];
    float sh = be[t] - mu * sc;
    scb[t] = sc;
    shb[t] = sh;
    sh_l[t] = sh;
    __syncthreads();
    float acc = 0.f;
    for (int k = 0; k < F; k++)
        acc += sh_l[k] * W2[(size_t)k * F + t];
    brow[t] = acc;
}

// ---------------- fold BN1 into W2 (transposed bf16) ----------------
__global__ __launch_bounds__(256) void fold_w2(
    const float* __restrict__ W2, const float* __restrict__ scb,
    unsigned short* __restrict__ WT2b)
{
    const int t = threadIdx.x;       // n
    const int k0 = blockIdx.x * 8;
#pragma unroll
    for (int kk = 0; kk < 8; kk++)
        WT2b[(size_t)t * F + k0 + kk] = f2bf(W2[(size_t)(k0 + kk) * F + t] * scb[k0 + kk]);
}

// ---------------- BN2 prep + fold into classifier weights, 1 block ----
__global__ __launch_bounds__(256) void fold_wc(
    const float* __restrict__ st, const float* __restrict__ g,
    const float* __restrict__ be, const float* __restrict__ Wc,
    const float* __restrict__ bc, float* __restrict__ Wcp, float* __restrict__ bcp)
{
    __shared__ float sc_l[F], sh_l[F];
    const int t = threadIdx.x;
    const float inv_n = 1.f / (float)N_NODES;
    float mu = st[t] * inv_n;
    float var = st[F + t] * inv_n - mu * mu;
    float sc = rsqrtf(var + BN_EPS) * g[t];
    sc_l[t] = sc;
    sh_l[t] = be[t] - mu * sc;
    __syncthreads();
#pragma unroll
    for (int o = 0; o < OUTC; o++)
        Wcp[t * OUTC + o] = Wc[t * OUTC + o] * sc_l[t];
    if (t < OUTC) {
        float acc = bc[t];
        for (int kk = 0; kk < F; kk++)
            acc += sh_l[kk] * Wc[kk * OUTC + t];
        bcp[t] = acc;
    }
}

// ---------------- classifier: [N,256]bf16 @ Wcp[256,10] + bcp --------
__global__ __launch_bounds__(256) void classifier(
    const unsigned short* __restrict__ Hb, const float* __restrict__ Wcp,
    const float* __restrict__ bcp, float* __restrict__ out)
{
    __shared__ float wls[F][OUTC + 1];
    const int t = threadIdx.x;
    for (int i = t; i < F * OUTC; i += 256)
        wls[i / OUTC][i % OUTC] = Wcp[i];
    __syncthreads();

    const int wave = t >> 6, lane = t & 63;
    const int n = blockIdx.x * 4 + wave;
    if (n >= N_NODES) return;

    float v[4];
#pragma unroll
    for (int j = 0; j < 4; j++)
        v[j] = bf2f(Hb[(size_t)n * F + j * 64 + lane]);

    float acc[OUTC];
#pragma unroll
    for (int o = 0; o < OUTC; o++) acc[o] = 0.f;
#pragma unroll
    for (int j = 0; j < 4; j++)
#pragma unroll
        for (int o = 0; o < OUTC; o++)
            acc[o] += v[j] * wls[j * 64 + lane][o];

#pragma unroll
    for (int off = 32; off > 0; off >>= 1)
#pragma unroll
        for (int o = 0; o < OUTC; o++)
            acc[o] += __shfl_xor(acc[o], off, 64);

    if (lane == 0) {
#pragma unroll
        for (int o = 0; o < OUTC; o++)
            out[(size_t)n * OUTC + o] = acc[o] + bcp[o];
    }
}

extern "C" void kernel_launch(void* const* d_in, const int* in_sizes, int n_in,
                              void* d_out, int out_size, void* d_ws, size_t ws_size,
                              hipStream_t stream)
{
    const float* x   = (const float*)d_in[0];
    const int*   ei  = (const int*)d_in[1];
    const float* W1  = (const float*)d_in[2];
    const float* as1 = (const float*)d_in[3];
    const float* ad1 = (const float*)d_in[4];
    const float* b1  = (const float*)d_in[5];
    const float* W2  = (const float*)d_in[6];
    const float* as2 = (const float*)d_in[7];
    const float* ad2 = (const float*)d_in[8];
    const float* b2  = (const float*)d_in[9];
    const float* g1  = (const float*)d_in[10];
    const float* be1 = (const float*)d_in[11];
    const float* g2  = (const float*)d_in[12];
    const float* be2 = (const float*)d_in[13];
    const float* Wc  = (const float*)d_in[14];
    const float* bc  = (const float*)d_in[15];
    float* out = (float*)d_out;

    char* w = (char*)d_ws;
    unsigned short* Xb   = (unsigned short*)w;   w += (size_t)N_NODES * 128 * 2;
    unsigned short* XWb  = (unsigned short*)w;   w += (size_t)N_NODES * F * 2;
    unsigned short* Hb   = (unsigned short*)w;   w += (size_t)N_NODES * F * 2;
    unsigned short* WT1b = (unsigned short*)w;   w += 256 * 128 * 2;
    unsigned short* WT2b = (unsigned short*)w;   w += 256 * 256 * 2;
    float* Wcp   = (float*)w;                    w += F * OUTC * 4;
    float* bcp   = (float*)w;                    w += 64;
    float* brow2 = (float*)w;                    w += F * 4;
    float* scb   = (float*)w;                    w += F * 4;
    float* shb   = (float*)w;                    w += F * 4;
    float* Sv    = (float*)w;                    w += (size_t)N_NODES * HEADS * 4;
    float* Dv    = (float*)w;                    w += (size_t)N_NODES * HEADS * 4;
    float* st1   = (float*)w;                    w += 2 * F * 4;   // st1,st2 contiguous
    float* st2   = (float*)w;                    w += 2 * F * 4;
    int* deg     = (int*)w;                      w += (size_t)N_NODES * 4;  // deg,cursor contiguous
    int* cursor  = (int*)w;                      w += (size_t)N_NODES * 4;
    int* rowp    = (int*)w;                      w += (size_t)(N_NODES + 1) * 4;
    int* bsum    = (int*)w;                      w += NB * 4;
    int* boff    = (int*)w;                      w += NB * 4;
    int* esrc    = (int*)w;                      /* E2 ints */

    const int grid_e    = (E2 + 255) / 256;
    const int grid_nw   = N_NODES / 4;           // 12500, exact
    const int grid_gemm = (N_NODES + 63) / 64;   // 782

    // ---- prep ----
    hipMemsetAsync(deg, 0, (size_t)N_NODES * 2 * 4, stream);   // deg + cursor
    hipMemsetAsync(st1, 0, 4 * F * 4, stream);                 // st1 + st2
    convert_x<<<(N_NODES * 128 / 4 + 255) / 256, 256, 0, stream>>>(x, Xb);
    convert_w1T<<<128, 256, 0, stream>>>(W1, WT1b);
    count_deg<<<grid_e, 256, 0, stream>>>(ei, deg);
    scan_blocks<<<NB, SB, 0, stream>>>(deg, rowp, bsum);
    scan_bsums<<<1, 64, 0, stream>>>(bsum, boff, rowp);
    scan_add<<<NB, SB, 0, stream>>>(rowp, boff);
    scatter_edges<<<grid_e, 256, 0, stream>>>(ei, rowp, cursor, esrc);

    // ---- layer 1 ----
    gemm_sd<128, false><<<grid_gemm, 256, 0, stream>>>(
        Xb, WT1b, nullptr, as1, ad1, XWb, Sv, Dv);
    gat_aggregate<<<grid_nw, 256, 0, stream>>>(rowp, esrc, Sv, Dv, XWb, b1, Hb, st1);
    prep_brow<<<1, 256, 0, stream>>>(st1, g1, be1, W2, scb, shb, brow2);
    fold_w2<<<32, 256, 0, stream>>>(W2, scb, WT2b);

    // ---- layer 2 ----
    gemm_sd<256, true><<<grid_gemm, 256, 0, stream>>>(
        Hb, WT2b, brow2, as2, ad2, XWb, Sv, Dv);
    gat_aggregate<<<grid_nw, 256, 0, stream>>>(rowp, esrc, Sv, Dv, XWb, b2, Hb, st2);
    fold_wc<<<1, 256, 0, stream>>>(st2, g2, be2, Wc, bc, Wcp, bcp);

    // ---- classifier ----
    classifier<<<grid_nw, 256, 0, stream>>>(Hb, Wcp, bcp, out);
}

// Round 10
// 554.649 us; speedup vs baseline: 1.7539x; 1.7539x over previous
//
#include <hip/hip_runtime.h>

#define N_NODES 50000
#define E_EDGES 1600000
#define E2 (E_EDGES + N_NODES)   // 1,650,000 with self loops
#define HEADS 4
#define F 256
#define OUTC 10
#define BN_EPS 1e-5f
#define NEG_SLOPE 0.2f
#define SB 1024                  // scan block size
#define NB ((N_NODES + SB - 1) / SB)   // 49 scan blocks
#define NSLICE 64                // stats atomic-spreading slices

static_assert(N_NODES % 4 == 0, "grid_nw exact");

typedef __attribute__((ext_vector_type(8))) short short8;
typedef __attribute__((ext_vector_type(4))) float f32x4;

__device__ __forceinline__ unsigned short f2bf(float f) {
    unsigned int u = __float_as_uint(f);
    unsigned int r = (u + 0x7fffu + ((u >> 16) & 1u)) >> 16;
    return (unsigned short)r;
}
__device__ __forceinline__ float bf2f(unsigned short b) {
    return __uint_as_float(((unsigned int)b) << 16);
}

// ---------------- convert X f32 -> bf16 ----------------
__global__ __launch_bounds__(256) void convert_x(
    const float* __restrict__ X, unsigned short* __restrict__ Xb)
{
    int i = blockIdx.x * blockDim.x + threadIdx.x;
    const int total = N_NODES * 128 / 4;
    if (i >= total) return;
    float4 v = reinterpret_cast<const float4*>(X)[i];
    ushort4 o = { f2bf(v.x), f2bf(v.y), f2bf(v.z), f2bf(v.w) };
    reinterpret_cast<ushort4*>(Xb)[i] = o;
}

// ---------------- convert W1 [128,256] f32 -> WT1b [256,128] bf16 ------
__global__ __launch_bounds__(256) void convert_w1T(
    const float* __restrict__ W1, unsigned short* __restrict__ WT)
{
    const int k = blockIdx.x;        // 128 blocks
    const int n = threadIdx.x;       // 256 threads, coalesced read
    WT[n * 128 + k] = f2bf(W1[k * 256 + n]);
}

// ---------------- CSR build (integer atomics only) ----------------
__global__ __launch_bounds__(256) void count_deg(
    const int* __restrict__ eidx, int* __restrict__ deg)
{
    int e = blockIdx.x * blockDim.x + threadIdx.x;
    if (e >= E2) return;
    int dst = (e < E_EDGES) ? eidx[E_EDGES + e] : e - E_EDGES;
    atomicAdd(&deg[dst], 1);
}

__global__ __launch_bounds__(SB) void scan_blocks(
    const int* __restrict__ deg, int* __restrict__ rowptr, int* __restrict__ bsum)
{
    __shared__ int sm[SB];
    const int t = threadIdx.x;
    const int idx = blockIdx.x * SB + t;
    int v = (idx < N_NODES) ? deg[idx] : 0;
    sm[t] = v;
    __syncthreads();
    for (int off = 1; off < SB; off <<= 1) {
        int u = (t >= off) ? sm[t - off] : 0;
        __syncthreads();
        sm[t] += u;
        __syncthreads();
    }
    if (idx < N_NODES) rowptr[idx] = sm[t] - v;
    if (t == SB - 1) bsum[blockIdx.x] = sm[t];
}

__global__ __launch_bounds__(64) void scan_bsums(
    const int* __restrict__ bsum, int* __restrict__ boff, int* __restrict__ rowptr)
{
    if (threadIdx.x == 0) {
        int run = 0;
        for (int b = 0; b < NB; b++) { boff[b] = run; run += bsum[b]; }
        rowptr[N_NODES] = run;
    }
}

__global__ __launch_bounds__(SB) void scan_add(
    int* __restrict__ rowptr, const int* __restrict__ boff)
{
    const int idx = blockIdx.x * SB + threadIdx.x;
    if (idx < N_NODES) rowptr[idx] += boff[blockIdx.x];
}

__global__ __launch_bounds__(256) void scatter_edges(
    const int* __restrict__ eidx, const int* __restrict__ rowptr,
    int* __restrict__ cursor, int* __restrict__ esrc)
{
    int e = blockIdx.x * blockDim.x + threadIdx.x;
    if (e >= E2) return;
    int src, dst;
    if (e < E_EDGES) { src = eidx[e]; dst = eidx[E_EDGES + e]; }
    else             { src = dst = e - E_EDGES; }
    int pos = atomicAdd(&cursor[dst], 1);
    esrc[rowptr[dst] + pos] = src;
}

// ------- MFMA GEMM + fused S/D: C = A@BT^T (+brow); S/D from f32 acc ---
template<int K, bool BROW>
__global__ __launch_bounds__(256) void gemm_sd(
    const unsigned short* __restrict__ A, const unsigned short* __restrict__ BT,
    const float* __restrict__ brow, const float* __restrict__ a_src,
    const float* __restrict__ a_dst, unsigned short* __restrict__ C,
    float* __restrict__ S, float* __restrict__ D)
{
    const int t = threadIdx.x;
    const int wave = t >> 6, lane = t & 63;
    const int lo = lane & 15, hi = lane >> 4;
    const int row0 = blockIdx.x * 64;
    const int nbase = wave * 64;

    int arow[4];
#pragma unroll
    for (int m = 0; m < 4; m++)
        arow[m] = min(row0 + m * 16 + lo, N_NODES - 1);   // never read unwritten ws

    f32x4 acc[4][4];
#pragma unroll
    for (int m = 0; m < 4; m++)
#pragma unroll
        for (int n = 0; n < 4; n++)
            acc[m][n] = (f32x4){0.f, 0.f, 0.f, 0.f};

    for (int k0 = 0; k0 < K; k0 += 32) {
        const int kk = k0 + hi * 8;
        short8 af[4], bfr[4];
#pragma unroll
        for (int m = 0; m < 4; m++)
            af[m] = *reinterpret_cast<const short8*>(A + (size_t)arow[m] * K + kk);
#pragma unroll
        for (int n = 0; n < 4; n++)
            bfr[n] = *reinterpret_cast<const short8*>(BT + (size_t)(nbase + n * 16 + lo) * K + kk);
#pragma unroll
        for (int m = 0; m < 4; m++)
#pragma unroll
            for (int n = 0; n < 4; n++)
                acc[m][n] = __builtin_amdgcn_mfma_f32_16x16x32_bf16(
                    af[m], bfr[n], acc[m][n], 0, 0, 0);
    }

    float bb[4], asv[4], adv[4];
#pragma unroll
    for (int n = 0; n < 4; n++) {
        int col = nbase + n * 16 + lo;
        bb[n]  = BROW ? brow[col] : 0.f;
        asv[n] = a_src[col];
        adv[n] = a_dst[col];
    }

#pragma unroll
    for (int m = 0; m < 4; m++) {
#pragma unroll
        for (int i = 0; i < 4; i++) {
            const int row = row0 + m * 16 + hi * 4 + i;
            const bool ok = row < N_NODES;
            float ps = 0.f, pd = 0.f;
#pragma unroll
            for (int n = 0; n < 4; n++) {
                float v = acc[m][n][i] + bb[n];
                ps += v * asv[n];
                pd += v * adv[n];
                if (ok) C[(size_t)row * F + nbase + n * 16 + lo] = f2bf(v);
            }
#pragma unroll
            for (int off = 1; off < 16; off <<= 1) {
                ps += __shfl_xor(ps, off, 64);
                pd += __shfl_xor(pd, off, 64);
            }
            if (lo == 0 && ok) {
                S[row * HEADS + wave] = ps;
                D[row * HEADS + wave] = pd;
            }
        }
    }
}

// ------- fused softmax + aggregation + bias + ReLU + sliced stats ------
// R6 inner loop (measured 113.8 us). Stats epilogue spread over NSLICE
// slices: block b atomically adds its 512 partials into stp[b&63][.],
// dropping per-address collisions 12500 -> ~195 (R9's 200us drain fix).
__global__ __launch_bounds__(256) void gat_aggregate(
    const int* __restrict__ rowptr, const int* __restrict__ esrc,
    const float* __restrict__ S, const float* __restrict__ D,
    const unsigned short* __restrict__ XWb, const float* __restrict__ bias,
    unsigned short* __restrict__ Hb, float* __restrict__ stp)
{
    __shared__ int   sbuf[4][64];
    __shared__ float wbuf[4][64][4];
    __shared__ float red_s[4][F];
    __shared__ float red_q[4][F];
    const int wv   = threadIdx.x >> 6;
    const int lane = threadIdx.x & 63;
    const int dst  = blockIdx.x * 4 + wv;        // always < N_NODES (N%4==0)
    const int beg = rowptr[dst], end = rowptr[dst + 1];
    const int h = lane >> 4;
    const float4 d4 = *reinterpret_cast<const float4*>(D + dst * HEADS);

    float ax = 0.f, ay = 0.f, az = 0.f, aw = 0.f, den = 0.f;

    for (int i = beg; i < end; i += 64) {
        const int nb = min(64, end - i);
        const bool valid = (i + lane < end);
        const int mysrc = valid ? esrc[i + lane] : 0;   // row 0 always valid
        float4 w4 = {0.f, 0.f, 0.f, 0.f};
        if (valid) {
            const float4 s4 = *reinterpret_cast<const float4*>(S + mysrc * HEADS);
            float z;
            z = s4.x + d4.x; w4.x = __expf(z > 0.f ? z : NEG_SLOPE * z);
            z = s4.y + d4.y; w4.y = __expf(z > 0.f ? z : NEG_SLOPE * z);
            z = s4.z + d4.z; w4.z = __expf(z > 0.f ? z : NEG_SLOPE * z);
            z = s4.w + d4.w; w4.w = __expf(z > 0.f ? z : NEG_SLOPE * z);
        }
        sbuf[wv][lane] = mysrc;
        *reinterpret_cast<float4*>(&wbuf[wv][lane][0]) = w4;

        int j = 0;
        for (; j + 7 < nb; j += 8) {
            int s0 = sbuf[wv][j + 0], s1 = sbuf[wv][j + 1];
            int s2 = sbuf[wv][j + 2], s3 = sbuf[wv][j + 3];
            int s4i = sbuf[wv][j + 4], s5 = sbuf[wv][j + 5];
            int s6 = sbuf[wv][j + 6], s7 = sbuf[wv][j + 7];
            float w0 = wbuf[wv][j + 0][h], w1 = wbuf[wv][j + 1][h];
            float w2 = wbuf[wv][j + 2][h], w3 = wbuf[wv][j + 3][h];
            float w4f = wbuf[wv][j + 4][h], w5 = wbuf[wv][j + 5][h];
            float w6 = wbuf[wv][j + 6][h], w7 = wbuf[wv][j + 7][h];
            ushort4 x0 = *reinterpret_cast<const ushort4*>(XWb + (size_t)s0 * F + lane * 4);
            ushort4 x1 = *reinterpret_cast<const ushort4*>(XWb + (size_t)s1 * F + lane * 4);
            ushort4 x2 = *reinterpret_cast<const ushort4*>(XWb + (size_t)s2 * F + lane * 4);
            ushort4 x3 = *reinterpret_cast<const ushort4*>(XWb + (size_t)s3 * F + lane * 4);
            ushort4 x4 = *reinterpret_cast<const ushort4*>(XWb + (size_t)s4i * F + lane * 4);
            ushort4 x5 = *reinterpret_cast<const ushort4*>(XWb + (size_t)s5 * F + lane * 4);
            ushort4 x6 = *reinterpret_cast<const ushort4*>(XWb + (size_t)s6 * F + lane * 4);
            ushort4 x7 = *reinterpret_cast<const ushort4*>(XWb + (size_t)s7 * F + lane * 4);
            ax += w0 * bf2f(x0.x) + w1 * bf2f(x1.x) + w2 * bf2f(x2.x) + w3 * bf2f(x3.x)
                + w4f * bf2f(x4.x) + w5 * bf2f(x5.x) + w6 * bf2f(x6.x) + w7 * bf2f(x7.x);
            ay += w0 * bf2f(x0.y) + w1 * bf2f(x1.y) + w2 * bf2f(x2.y) + w3 * bf2f(x3.y)
                + w4f * bf2f(x4.y) + w5 * bf2f(x5.y) + w6 * bf2f(x6.y) + w7 * bf2f(x7.y);
            az += w0 * bf2f(x0.z) + w1 * bf2f(x1.z) + w2 * bf2f(x2.z) + w3 * bf2f(x3.z)
                + w4f * bf2f(x4.z) + w5 * bf2f(x5.z) + w6 * bf2f(x6.z) + w7 * bf2f(x7.z);
            aw += w0 * bf2f(x0.w) + w1 * bf2f(x1.w) + w2 * bf2f(x2.w) + w3 * bf2f(x3.w)
                + w4f * bf2f(x4.w) + w5 * bf2f(x5.w) + w6 * bf2f(x6.w) + w7 * bf2f(x7.w);
            den += ((w0 + w1) + (w2 + w3)) + ((w4f + w5) + (w6 + w7));
        }
        for (; j < nb; j++) {
            int   src = sbuf[wv][j];
            float w = wbuf[wv][j][h];
            ushort4 xv = *reinterpret_cast<const ushort4*>(XWb + (size_t)src * F + lane * 4);
            ax += w * bf2f(xv.x); ay += w * bf2f(xv.y);
            az += w * bf2f(xv.z); aw += w * bf2f(xv.w);
            den += w;
        }
    }

    const float inv = 1.f / (den + 1e-16f);
    float4 bv = *reinterpret_cast<const float4*>(bias + lane * 4);
    float v0 = ax * inv + bv.x, v1 = ay * inv + bv.y;
    float v2 = az * inv + bv.z, v3 = aw * inv + bv.w;
    v0 = v0 > 0.f ? v0 : 0.f; v1 = v1 > 0.f ? v1 : 0.f;
    v2 = v2 > 0.f ? v2 : 0.f; v3 = v3 > 0.f ? v3 : 0.f;
    ushort4 o = { f2bf(v0), f2bf(v1), f2bf(v2), f2bf(v3) };
    *reinterpret_cast<ushort4*>(Hb + (size_t)dst * F + lane * 4) = o;

    f32x4 rs = {v0, v1, v2, v3};
    f32x4 rq = {v0 * v0, v1 * v1, v2 * v2, v3 * v3};
    *reinterpret_cast<f32x4*>(&red_s[wv][lane * 4]) = rs;
    *reinterpret_cast<f32x4*>(&red_q[wv][lane * 4]) = rq;
    __syncthreads();
    // block stats -> SLICED atomics (spread contention NSLICE-ways)
    const int ch = threadIdx.x;
    float s = (red_s[0][ch] + red_s[1][ch]) + (red_s[2][ch] + red_s[3][ch]);
    float q = (red_q[0][ch] + red_q[1][ch]) + (red_q[2][ch] + red_q[3][ch]);
    float* slice = stp + (size_t)(blockIdx.x & (NSLICE - 1)) * (2 * F);
    atomicAdd(&slice[ch], s);
    atomicAdd(&slice[F + ch], q);
}

// ---------------- BN prep + brow (layer 1 -> layer 2 fold), 1 block ----
__global__ __launch_bounds__(256) void prep_brow(
    const float* __restrict__ stp, const float* __restrict__ g,
    const float* __restrict__ be, const float* __restrict__ W2,
    float* __restrict__ scb, float* __restrict__ shb, float* __restrict__ brow)
{
    __shared__ float sh_l[F];
    const int t = threadIdx.x;
    float s = 0.f, q = 0.f;
    for (int b = 0; b < NSLICE; b++) {       // fixed order
        s += stp[(size_t)b * 2 * F + t];
        q += stp[(size_t)b * 2 * F + F + t];
    }
    const float inv_n = 1.f / (float)N_NODES;
    float mu = s * inv_n;
    float var = q * inv_n - mu * mu;
    float sc = rsqrtf(var + BN_EPS) * g[t];
    float sh = be[t] - mu * sc;
    scb[t] = sc;
    shb[t] = sh;
    sh_l[t] = sh;
    __syncthreads();
    float acc = 0.f;
    for (int k = 0; k < F; k++)
        acc += sh_l[k] * W2[(size_t)k * F + t];
    brow[t] = acc;
}

// ---------------- fold BN1 into W2 (transposed bf16) ----------------
__global__ __launch_bounds__(256) void fold_w2(
    const float* __restrict__ W2, const float* __restrict__ scb,
    unsigned short* __restrict__ WT2b)
{
    const int t = threadIdx.x;       // n
    const int k0 = blockIdx.x * 8;
#pragma unroll
    for (int kk = 0; kk < 8; kk++)
        WT2b[(size_t)t * F + k0 + kk] = f2bf(W2[(size_t)(k0 + kk) * F + t] * scb[k0 + kk]);
}

// ---------------- BN2 prep + fold into classifier weights, 1 block ----
__global__ __launch_bounds__(256) void fold_wc(
    const float* __restrict__ stp, const float* __restrict__ g,
    const float* __restrict__ be, const float* __restrict__ Wc,
    const float* __restrict__ bc, float* __restrict__ Wcp, float* __restrict__ bcp)
{
    __shared__ float sc_l[F], sh_l[F];
    const int t = threadIdx.x;
    float s = 0.f, q = 0.f;
    for (int b = 0; b < NSLICE; b++) {       // fixed order
        s += stp[(size_t)b * 2 * F + t];
        q += stp[(size_t)b * 2 * F + F + t];
    }
    const float inv_n = 1.f / (float)N_NODES;
    float mu = s * inv_n;
    float var = q * inv_n - mu * mu;
    float sc = rsqrtf(var + BN_EPS) * g[t];
    sc_l[t] = sc;
    sh_l[t] = be[t] - mu * sc;
    __syncthreads();
#pragma unroll
    for (int o = 0; o < OUTC; o++)
        Wcp[t * OUTC + o] = Wc[t * OUTC + o] * sc_l[t];
    if (t < OUTC) {
        float acc = bc[t];
        for (int kk = 0; kk < F; kk++)
            acc += sh_l[kk] * Wc[kk * OUTC + t];
        bcp[t] = acc;
    }
}

// ---------------- classifier: [N,256]bf16 @ Wcp[256,10] + bcp --------
__global__ __launch_bounds__(256) void classifier(
    const unsigned short* __restrict__ Hb, const float* __restrict__ Wcp,
    const float* __restrict__ bcp, float* __restrict__ out)
{
    __shared__ float wls[F][OUTC + 1];
    const int t = threadIdx.x;
    for (int i = t; i < F * OUTC; i += 256)
        wls[i / OUTC][i % OUTC] = Wcp[i];
    __syncthreads();

    const int wave = t >> 6, lane = t & 63;
    const int n = blockIdx.x * 4 + wave;
    if (n >= N_NODES) return;

    float v[4];
#pragma unroll
    for (int j = 0; j < 4; j++)
        v[j] = bf2f(Hb[(size_t)n * F + j * 64 + lane]);

    float acc[OUTC];
#pragma unroll
    for (int o = 0; o < OUTC; o++) acc[o] = 0.f;
#pragma unroll
    for (int j = 0; j < 4; j++)
#pragma unroll
        for (int o = 0; o < OUTC; o++)
            acc[o] += v[j] * wls[j * 64 + lane][o];

#pragma unroll
    for (int off = 32; off > 0; off >>= 1)
#pragma unroll
        for (int o = 0; o < OUTC; o++)
            acc[o] += __shfl_xor(acc[o], off, 64);

    if (lane == 0) {
#pragma unroll
        for (int o = 0; o < OUTC; o++)
            out[(size_t)n * OUTC + o] = acc[o] + bcp[o];
    }
}

extern "C" void kernel_launch(void* const* d_in, const int* in_sizes, int n_in,
                              void* d_out, int out_size, void* d_ws, size_t ws_size,
                              hipStream_t stream)
{
    const float* x   = (const float*)d_in[0];
    const int*   ei  = (const int*)d_in[1];
    const float* W1  = (const float*)d_in[2];
    const float* as1 = (const float*)d_in[3];
    const float* ad1 = (const float*)d_in[4];
    const float* b1  = (const float*)d_in[5];
    const float* W2  = (const float*)d_in[6];
    const float* as2 = (const float*)d_in[7];
    const float* ad2 = (const float*)d_in[8];
    const float* b2  = (const float*)d_in[9];
    const float* g1  = (const float*)d_in[10];
    const float* be1 = (const float*)d_in[11];
    const float* g2  = (const float*)d_in[12];
    const float* be2 = (const float*)d_in[13];
    const float* Wc  = (const float*)d_in[14];
    const float* bc  = (const float*)d_in[15];
    float* out = (float*)d_out;

    char* w = (char*)d_ws;
    unsigned short* Xb   = (unsigned short*)w;   w += (size_t)N_NODES * 128 * 2;
    unsigned short* XWb  = (unsigned short*)w;   w += (size_t)N_NODES * F * 2;
    unsigned short* Hb   = (unsigned short*)w;   w += (size_t)N_NODES * F * 2;
    unsigned short* WT1b = (unsigned short*)w;   w += 256 * 128 * 2;
    unsigned short* WT2b = (unsigned short*)w;   w += 256 * 256 * 2;
    float* Wcp   = (float*)w;                    w += F * OUTC * 4;
    float* bcp   = (float*)w;                    w += 64;
    float* brow2 = (float*)w;                    w += F * 4;
    float* scb   = (float*)w;                    w += F * 4;
    float* shb   = (float*)w;                    w += F * 4;
    float* Sv    = (float*)w;                    w += (size_t)N_NODES * HEADS * 4;
    float* Dv    = (float*)w;                    w += (size_t)N_NODES * HEADS * 4;
    float* stp1  = (float*)w;                    w += (size_t)NSLICE * 2 * F * 4;  // sliced stats L1
    float* stp2  = (float*)w;                    w += (size_t)NSLICE * 2 * F * 4;  // sliced stats L2
    int* deg     = (int*)w;                      w += (size_t)N_NODES * 4;  // deg,cursor contiguous
    int* cursor  = (int*)w;                      w += (size_t)N_NODES * 4;
    int* rowp    = (int*)w;                      w += (size_t)(N_NODES + 1) * 4;
    int* bsum    = (int*)w;                      w += NB * 4;
    int* boff    = (int*)w;                      w += NB * 4;
    int* esrc    = (int*)w;                      /* E2 ints */

    const int grid_e    = (E2 + 255) / 256;
    const int grid_nw   = N_NODES / 4;           // 12500, exact
    const int grid_gemm = (N_NODES + 63) / 64;   // 782

    // ---- prep ----
    hipMemsetAsync(deg, 0, (size_t)N_NODES * 2 * 4, stream);           // deg + cursor
    hipMemsetAsync(stp1, 0, (size_t)2 * NSLICE * 2 * F * 4, stream);   // stp1 + stp2
    convert_x<<<(N_NODES * 128 / 4 + 255) / 256, 256, 0, stream>>>(x, Xb);
    convert_w1T<<<128, 256, 0, stream>>>(W1, WT1b);
    count_deg<<<grid_e, 256, 0, stream>>>(ei, deg);
    scan_blocks<<<NB, SB, 0, stream>>>(deg, rowp, bsum);
    scan_bsums<<<1, 64, 0, stream>>>(bsum, boff, rowp);
    scan_add<<<NB, SB, 0, stream>>>(rowp, boff);
    scatter_edges<<<grid_e, 256, 0, stream>>>(ei, rowp, cursor, esrc);

    // ---- layer 1 ----
    gemm_sd<128, false><<<grid_gemm, 256, 0, stream>>>(
        Xb, WT1b, nullptr, as1, ad1, XWb, Sv, Dv);
    gat_aggregate<<<grid_nw, 256, 0, stream>>>(rowp, esrc, Sv, Dv, XWb, b1, Hb, stp1);
    prep_brow<<<1, 256, 0, stream>>>(stp1, g1, be1, W2, scb, shb, brow2);
    fold_w2<<<32, 256, 0, stream>>>(W2, scb, WT2b);

    // ---- layer 2 ----
    gemm_sd<256, true><<<grid_gemm, 256, 0, stream>>>(
        Hb, WT2b, brow2, as2, ad2, XWb, Sv, Dv);
    gat_aggregate<<<grid_nw, 256, 0, stream>>>(rowp, esrc, Sv, Dv, XWb, b2, Hb, stp2);
    fold_wc<<<1, 256, 0, stream>>>(stp2, g2, be2, Wc, bc, Wcp, bcp);

    // ---- classifier ----
    classifier<<<grid_nw, 256, 0, stream>>>(Hb, Wcp, bcp, out);
}